// Round 4
// baseline (104.784 us; speedup 1.0000x reference)
//
#include <hip/hip_runtime.h>

typedef __bf16 bf16_t;
typedef bf16_t bf16x8 __attribute__((ext_vector_type(8)));
typedef float f32x4 __attribute__((ext_vector_type(4)));
typedef unsigned short ushort_t;
typedef unsigned int uint_t;

#define C10L2E 14.4269504088896340736f   // 10 * log2(e)
#define LN2    0.69314718055994530942f
#define NEG_BIG -3.0e38f
#define M0     -1.0e30f
#define THR_L2 11.5415603f               // 0.8 raw logit units in log2-space

static __device__ __forceinline__ float fexp2(float x){ return __builtin_amdgcn_exp2f(x); }
static __device__ __forceinline__ float flog2(float x){ return __builtin_amdgcn_logf(x); }

#define GLOAD16(g, l) __builtin_amdgcn_global_load_lds( \
    (const __attribute__((address_space(1))) void*)(g), \
    (__attribute__((address_space(3))) void*)(l), 16, 0, 0)

// ---------------- fp32 -> bf16 (RNE) ----------------
static __device__ __forceinline__ ushort_t f2bf1(float f) {
    uint_t u = __float_as_uint(f);
    uint_t r = (u + 0x7fffu + ((u >> 16) & 1u)) >> 16;
    return (ushort_t)r;
}

// ---------------- prep: bf16 convert + label scatter (fused) ----------------
__global__ void prep_kernel(const float* __restrict__ feat, const int* __restrict__ labels,
                            ushort_t* __restrict__ Fb, int* __restrict__ cnt,
                            int* __restrict__ idxl) {
    int i = blockIdx.x * 256 + threadIdx.x;        // 0..524287 float4s
    float4 f = reinterpret_cast<const float4*>(feat)[i];
    ushort4 o;
    o.x = f2bf1(f.x); o.y = f2bf1(f.y); o.z = f2bf1(f.z); o.w = f2bf1(f.w);
    reinterpret_cast<ushort4*>(Fb)[i] = o;
    if (i < 4096) {
        int lab = labels[i];
        int p = atomicAdd(&cnt[lab], 1);
        if (p < 64) idxl[lab * 64 + p] = i;
    }
}

// ---------------- per-class term: (|G_c|^2 - sum|f_i|^2) / (2*cnt-1) ----------------
__global__ void classterm_kernel(const float* __restrict__ feat, const int* __restrict__ cnt,
                                 const int* __restrict__ idxl, float* __restrict__ term) {
    int c = blockIdx.x;
    int lane = threadIdx.x;                         // 0..63
    int n = cnt[c];
    float4 g4 = make_float4(0.f, 0.f, 0.f, 0.f);
    float n2 = 0.f;
    for (int e = 0; e < n; ++e) {
        int r = idxl[c * 64 + e];
        float4 f0 = reinterpret_cast<const float4*>(feat)[(size_t)r * 64 + lane];
        float4 f1 = reinterpret_cast<const float4*>(feat)[(size_t)(r + 4096) * 64 + lane];
        g4.x += f0.x + f1.x; g4.y += f0.y + f1.y;
        g4.z += f0.z + f1.z; g4.w += f0.w + f1.w;
        n2 += f0.x*f0.x + f0.y*f0.y + f0.z*f0.z + f0.w*f0.w
            + f1.x*f1.x + f1.y*f1.y + f1.z*f1.z + f1.w*f1.w;
    }
    float gg = g4.x*g4.x + g4.y*g4.y + g4.z*g4.z + g4.w*g4.w;
    #pragma unroll
    for (int d = 1; d < 64; d <<= 1) {
        gg += __shfl_xor(gg, d, 64);
        n2 += __shfl_xor(n2, d, 64);
    }
    if (lane == 0) term[c] = (n > 0) ? (gg - n2) / (float)(2 * n - 1) : 0.0f;
}

// ---------------- main MFMA kernel ----------------
// grid (64,4) = 256 blocks = 1/CU. 512 threads = 8 waves (2x4), wave tile 64x64.
// A-fragments held in registers (128 VGPR/lane), loaded once from global (L2-resident,
// 64B-coalesced). LDS = 4 x 32KB B quarter-buffers (K=64 each); barrier every 2 phases;
// stages issued a full phase-pair ahead. 16B-slot XOR swizzle on B.
__global__ __launch_bounds__(512, 2) void supcon_main(
        const ushort_t* __restrict__ Fb, float* __restrict__ part) {
    extern __shared__ char lds[];                   // 4 x 32768 B buffers

    const int tid  = threadIdx.x;
    const int lane = tid & 63;
    const int wid  = tid >> 6;
    const int wr   = (wid >> 2) * 64;
    const int wc   = (wid & 3) * 64;
    const int g    = lane >> 4;
    const int l15  = lane & 15;
    const int r0 = blockIdx.x * 128;
    const int c0 = blockIdx.y * 2048;

    // ---- A fragments: rows (r0+wr .. +63) x K=256, direct global -> regs ----
    bf16x8 a[4][8];
    #pragma unroll
    for (int m = 0; m < 4; ++m) {
        const ushort_t* bA = Fb + (size_t)(r0 + wr + m * 16 + l15) * 256 + g * 8;
        #pragma unroll
        for (int kq = 0; kq < 8; ++kq)
            a[m][kq] = *reinterpret_cast<const bf16x8*>(bA + kq * 32);
    }

    // ---- stage helper: B quarter (cols j0..j0+255, k-quarter qn) -> buffer bb ----
    auto stage = [&](int j0, int qn, int bb) {
        #pragma unroll
        for (int i = 0; i < 4; ++i) {
            int c = (wid * 4 + i) * 64 + lane;      // 0..2047 16B-chunks
            int col = c >> 3, ps = c & 7;
            int lslot = ps ^ (col & 7);             // inverse swizzle on source
            GLOAD16(Fb + (size_t)(j0 + col) * 256 + qn * 64 + lslot * 8,
                    lds + bb * 32768 + c * 16);
        }
    };

    stage(c0, 0, 0);
    stage(c0, 1, 1);
    __syncthreads();

    float ML2[16], S[16];
    #pragma unroll
    for (int x = 0; x < 16; ++x) { ML2[x] = M0; S[x] = 0.0f; }

    f32x4 acc[4][4];

    #pragma unroll 1
    for (int t = 0; t < 8; ++t) {
        const int j0 = c0 + t * 256;
        #pragma unroll
        for (int q = 0; q < 4; ++q) {
            // prefetch a full pair ahead
            if (q == 0) { stage(j0, 2, 2); stage(j0, 3, 3); }
            else if (q == 2 && t < 7) { stage(j0 + 256, 0, 0); stage(j0 + 256, 1, 1); }

            if (q == 0) {
                #pragma unroll
                for (int m = 0; m < 4; ++m)
                    #pragma unroll
                    for (int n = 0; n < 4; ++n)
                        #pragma unroll
                        for (int w = 0; w < 4; ++w) acc[m][n][w] = 0.0f;
            }

            const char* Bp = lds + q * 32768;
            #pragma unroll
            for (int kk = 0; kk < 2; ++kk) {
                bf16x8 b[4];
                int pB = (kk * 4 + g) ^ (l15 & 7);
                #pragma unroll
                for (int n = 0; n < 4; ++n)
                    b[n] = *reinterpret_cast<const bf16x8*>(Bp + (wc + n * 16 + l15) * 128 + pB * 16);
                #pragma unroll
                for (int m = 0; m < 4; ++m)
                    #pragma unroll
                    for (int n = 0; n < 4; ++n)
                        acc[m][n] = __builtin_amdgcn_mfma_f32_16x16x32_bf16(a[m][q * 2 + kk], b[n], acc[m][n], 0, 0, 0);
            }

            if (q == 3) {
                const bool diag = (j0 == (r0 & ~255));
                const int jc = j0 + wc + l15;
                #pragma unroll
                for (int m = 0; m < 4; ++m) {
                    #pragma unroll
                    for (int v = 0; v < 4; ++v) {
                        const int idx = m * 4 + v;
                        float x0 = acc[m][0][v], x1 = acc[m][1][v];
                        float x2 = acc[m][2][v], x3 = acc[m][3][v];
                        if (diag) {
                            int i = r0 + wr + m * 16 + g * 4 + v;
                            if (jc      == i) x0 = NEG_BIG;
                            if (jc + 16 == i) x1 = NEG_BIG;
                            if (jc + 32 == i) x2 = NEG_BIG;
                            if (jc + 48 == i) x3 = NEG_BIG;
                        }
                        float tm = fmaxf(fmaxf(x0, x1), fmaxf(x2, x3));
                        float cc = tm * C10L2E;
                        float ml = ML2[idx];
                        if (cc > ml + THR_L2) {          // rare rescale (defer-max)
                            S[idx] *= fexp2(ml - cc);
                            ml = cc;
                            ML2[idx] = cc;
                        }
                        S[idx] += fexp2(fmaf(x0, C10L2E, -ml)) + fexp2(fmaf(x1, C10L2E, -ml))
                                + fexp2(fmaf(x2, C10L2E, -ml)) + fexp2(fmaf(x3, C10L2E, -ml));
                    }
                }
            }
            if (q & 1) __syncthreads();
        }
    }

    // ---- cross-lane merge within 16-lane groups, store partials ----
    const int slot = blockIdx.y * 4 + (wid & 3);
    #pragma unroll
    for (int idx = 0; idx < 16; ++idx) {
        float m_ = ML2[idx], s_ = S[idx];
        #pragma unroll
        for (int d = 1; d < 16; d <<= 1) {
            float mo = __shfl_xor(m_, d, 64);
            float so = __shfl_xor(s_, d, 64);
            float nm = fmaxf(m_, mo);
            s_ = s_ * fexp2(m_ - nm) + so * fexp2(mo - nm);
            m_ = nm;
        }
        if (l15 == 0) {
            int i = r0 + wr + (idx >> 2) * 16 + g * 4 + (idx & 3);
            float2 val; val.x = m_; val.y = s_;
            *reinterpret_cast<float2*>(part + ((size_t)i * 16 + slot) * 2) = val;
        }
    }
}

// ---------------- combine + final (fused): lse merge, class terms, last-block writes out ----
// 512 blocks x 256 threads; 16 rows/block
__global__ void combine_kernel(const float* __restrict__ part, const float* __restrict__ term,
                               float* __restrict__ acc, int* __restrict__ cntr,
                               float* __restrict__ out) {
    __shared__ float sm[16];
    int tid = threadIdx.x;
    int row = blockIdx.x * 16 + (tid >> 4);
    int l16 = tid & 15;
    float2 v = reinterpret_cast<const float2*>(part)[(size_t)row * 16 + l16];
    float m_ = v.x, s_ = v.y;
    #pragma unroll
    for (int d = 1; d < 16; d <<= 1) {
        float mo = __shfl_xor(m_, d, 64);
        float so = __shfl_xor(s_, d, 64);
        float nm = fmaxf(m_, mo);
        s_ = s_ * fexp2(m_ - nm) + so * fexp2(mo - nm);
        m_ = nm;
    }
    if (l16 == 0) sm[tid >> 4] = LN2 * (m_ + flog2(s_));
    __syncthreads();
    if (tid == 0) {
        float a = 0.f;
        #pragma unroll
        for (int i = 0; i < 16; ++i) a += sm[i];
        a -= 10.0f * term[blockIdx.x];
        if (blockIdx.x < 488) a -= 10.0f * term[512 + blockIdx.x];
        atomicAdd(acc, a);
        __threadfence();
        int old = atomicAdd(cntr, 1);
        if (old == 511) {
            __threadfence();
            float tot = atomicAdd(acc, 0.0f);
            out[0] = tot * (0.1f / 8192.0f);
        }
    }
}

extern "C" void kernel_launch(void* const* d_in, const int* in_sizes, int n_in,
                              void* d_out, int out_size, void* d_ws, size_t ws_size,
                              hipStream_t stream) {
    const float* feat = (const float*)d_in[0];    // 8192 x 256 fp32
    const int* labels = (const int*)d_in[1];      // 4096
    float* out = (float*)d_out;

    char* ws = (char*)d_ws;
    ushort_t* Fb = (ushort_t*)ws;                                // 4 MB
    float* part  = (float*)(ws + (4u << 20));                    // 1 MB
    int* cnt     = (int*)(ws + (5u << 20));                      // 4 KB
    float* acc   = (float*)(ws + (5u << 20) + 4096);             // 4 B
    int* cntr    = (int*)(ws + (5u << 20) + 4100);               // 4 B
    int* idxl    = (int*)(ws + (5u << 20) + 8192);               // 256 KB
    float* term  = (float*)(ws + (5u << 20) + 8192 + 262144);    // 4 KB

    hipMemsetAsync(ws + (5u << 20), 0, 8192, stream);            // cnt + acc + cntr
    prep_kernel<<<2048, 256, 0, stream>>>(feat, labels, Fb, cnt, idxl);
    classterm_kernel<<<1000, 64, 0, stream>>>(feat, cnt, idxl, term);
    dim3 grid(64, 4);
    supcon_main<<<grid, 512, 131072, stream>>>(Fb, part);
    combine_kernel<<<512, 256, 0, stream>>>(part, term, acc, cntr, out);
}

// Round 5
// 80.889 us; speedup vs baseline: 1.2954x; 1.2954x over previous
//
#include <hip/hip_runtime.h>

typedef __bf16 bf16_t;
typedef bf16_t bf16x8 __attribute__((ext_vector_type(8)));
typedef float f32x4 __attribute__((ext_vector_type(4)));
typedef unsigned short ushort_t;
typedef unsigned int uint_t;

#define C10L2E 14.4269504088896340736f   // 10 * log2(e)
#define LN2    0.69314718055994530942f
#define NEG_BIG -3.0e38f
#define M0     -1.0e30f
#define THR_L2 11.5415603f               // 0.8 raw logit units in log2-space

static __device__ __forceinline__ float fexp2(float x){ return __builtin_amdgcn_exp2f(x); }
static __device__ __forceinline__ float flog2(float x){ return __builtin_amdgcn_logf(x); }

#define GLOAD16(g, l) __builtin_amdgcn_global_load_lds( \
    (const __attribute__((address_space(1))) void*)(g), \
    (__attribute__((address_space(3))) void*)(l), 16, 0, 0)

#define WAITV(n) asm volatile("s_waitcnt vmcnt(" #n ")" ::: "memory")

// ---------------- fp32 -> bf16 (RNE) ----------------
static __device__ __forceinline__ ushort_t f2bf1(float f) {
    uint_t u = __float_as_uint(f);
    uint_t r = (u + 0x7fffu + ((u >> 16) & 1u)) >> 16;
    return (ushort_t)r;
}

// ---------------- prep: bf16 convert + label scatter (fused) ----------------
__global__ void prep_kernel(const float* __restrict__ feat, const int* __restrict__ labels,
                            ushort_t* __restrict__ Fb, int* __restrict__ cnt,
                            int* __restrict__ idxl) {
    int i = blockIdx.x * 256 + threadIdx.x;        // 0..524287 float4s
    float4 f = reinterpret_cast<const float4*>(feat)[i];
    ushort4 o;
    o.x = f2bf1(f.x); o.y = f2bf1(f.y); o.z = f2bf1(f.z); o.w = f2bf1(f.w);
    reinterpret_cast<ushort4*>(Fb)[i] = o;
    if (i < 4096) {
        int lab = labels[i];
        int p = atomicAdd(&cnt[lab], 1);
        if (p < 64) idxl[lab * 64 + p] = i;
    }
}

// ---------------- per-class term: (|G_c|^2 - sum|f_i|^2) / (2*cnt-1) ----------------
__global__ void classterm_kernel(const float* __restrict__ feat, const int* __restrict__ cnt,
                                 const int* __restrict__ idxl, float* __restrict__ term) {
    int c = blockIdx.x;
    int lane = threadIdx.x;                         // 0..63
    int n = cnt[c];
    float4 g4 = make_float4(0.f, 0.f, 0.f, 0.f);
    float n2 = 0.f;
    for (int e = 0; e < n; ++e) {
        int r = idxl[c * 64 + e];
        float4 f0 = reinterpret_cast<const float4*>(feat)[(size_t)r * 64 + lane];
        float4 f1 = reinterpret_cast<const float4*>(feat)[(size_t)(r + 4096) * 64 + lane];
        g4.x += f0.x + f1.x; g4.y += f0.y + f1.y;
        g4.z += f0.z + f1.z; g4.w += f0.w + f1.w;
        n2 += f0.x*f0.x + f0.y*f0.y + f0.z*f0.z + f0.w*f0.w
            + f1.x*f1.x + f1.y*f1.y + f1.z*f1.z + f1.w*f1.w;
    }
    float gg = g4.x*g4.x + g4.y*g4.y + g4.z*g4.z + g4.w*g4.w;
    #pragma unroll
    for (int d = 1; d < 64; d <<= 1) {
        gg += __shfl_xor(gg, d, 64);
        n2 += __shfl_xor(n2, d, 64);
    }
    if (lane == 0) term[c] = (n > 0) ? (gg - n2) / (float)(2 * n - 1) : 0.0f;
}

// ---------------- main MFMA kernel ----------------
// grid (64,4) = 256 blocks = 1/CU. 512 threads = 8 waves (2x4), wave tile 64x64.
// LDS 128KB: A full-K (128x256 bf16, XOR-swizzled, 64KB) + 4 x 16KB B K-eighth buffers.
// 64 phases (8 col-tiles x 8 K-eighths). Pipeline: stage issued 2 phases ahead via
// global_load_lds; counted s_waitcnt vmcnt(4) + single raw s_barrier per phase (T3+T4).
// Buffer rotation (4 bufs, overwrite target last read 2 phases ago) makes it race-free.
__global__ __launch_bounds__(512, 1) void supcon_main(
        const ushort_t* __restrict__ Fb, float* __restrict__ part) {
    extern __shared__ char lds[];
    char* As = lds;                     // [128 rows][32 slots of 16B]
    char* Bb = lds + 65536;             // 4 x [256 cols][4 slots of 16B]

    const int tid  = threadIdx.x;
    const int lane = tid & 63;
    const int wid  = tid >> 6;
    const int wr   = (wid >> 2) * 64;
    const int wc   = (wid & 3) * 64;
    const int g    = lane >> 4;
    const int l15  = lane & 15;
    const int r0 = blockIdx.x * 128;
    const int c0 = blockIdx.y * 2048;

    // ---- stage A once (8 chunks/thread) ----
    #pragma unroll
    for (int i = 0; i < 8; ++i) {
        int c = (wid * 8 + i) * 64 + lane;          // 0..4095 16B-chunks
        int row = c >> 5, sl = c & 31;
        int lslot = (sl & 16) | ((sl ^ row) & 15);  // inverse swizzle on source
        GLOAD16(Fb + (size_t)(r0 + row) * 256 + lslot * 8, As + c * 16);
    }

    // ---- B staging geometry (2 chunks/thread), swizzle slot p ^ ((col>>1)&3) ----
    int bofs0, bofs1, bdst0, bdst1;
    {
        int c = tid;                                 // chunk 0..511
        int col = c >> 2, pp = c & 3;
        bofs0 = col * 256 + (pp ^ ((col >> 1) & 3)) * 8;
        bdst0 = c * 16;
        c = 512 + tid;
        col = c >> 2; pp = c & 3;
        bofs1 = col * 256 + (pp ^ ((col >> 1) & 3)) * 8;
        bdst1 = c * 16;
    }
    auto stageB = [&](int p) {                       // phase index 0..63
        const ushort_t* base = Fb + (size_t)(c0 + (p >> 3) * 256) * 256 + (p & 7) * 32;
        char* Bd = Bb + (p & 3) * 16384;
        GLOAD16(base + bofs0, Bd + bdst0);
        GLOAD16(base + bofs1, Bd + bdst1);
    };

    stageB(0); stageB(1);

    float ML2[16], S[16];
    #pragma unroll
    for (int x = 0; x < 16; ++x) { ML2[x] = M0; S[x] = 0.0f; }

    f32x4 acc[4][4];

    #pragma unroll 1
    for (int t = 0; t < 8; ++t) {
        const int j0 = c0 + t * 256;
        #pragma unroll
        for (int e = 0; e < 8; ++e) {
            const int p = t * 8 + e;
            // issue stage 2 phases ahead, then counted wait, then barrier
            if (e <= 5) {
                stageB(p + 2);
                WAITV(4);
            } else if (e == 6) {
                if (t < 7) { stageB(p + 2); WAITV(4); } else { WAITV(2); }
            } else {
                if (t < 7) { stageB(p + 2); WAITV(4); } else { WAITV(0); }
            }
            __builtin_amdgcn_s_barrier();
            __builtin_amdgcn_sched_barrier(0);

            // ---- ds reads: 4 A + 4 B b128 per lane ----
            bf16x8 a[4], b[4];
            {
                int sA = e * 4 + g;
                int pA = (sA & 16) | ((sA ^ l15) & 15);
                #pragma unroll
                for (int m = 0; m < 4; ++m)
                    a[m] = *reinterpret_cast<const bf16x8*>(As + (wr + m * 16 + l15) * 512 + pA * 16);
                const char* Bp = Bb + (p & 3) * 16384;
                int pB = g ^ ((l15 >> 1) & 3);
                #pragma unroll
                for (int n = 0; n < 4; ++n)
                    b[n] = *reinterpret_cast<const bf16x8*>(Bp + (wc + n * 16 + l15) * 64 + pB * 16);
            }

            if (e == 0) {
                #pragma unroll
                for (int m = 0; m < 4; ++m)
                    #pragma unroll
                    for (int n = 0; n < 4; ++n)
                        #pragma unroll
                        for (int w = 0; w < 4; ++w) acc[m][n][w] = 0.0f;
            }
            #pragma unroll
            for (int m = 0; m < 4; ++m)
                #pragma unroll
                for (int n = 0; n < 4; ++n)
                    acc[m][n] = __builtin_amdgcn_mfma_f32_16x16x32_bf16(a[m], b[n], acc[m][n], 0, 0, 0);

            if (e == 7) {
                const bool diag = (j0 == (r0 & ~255));
                const int jc = j0 + wc + l15;
                #pragma unroll
                for (int m = 0; m < 4; ++m) {
                    #pragma unroll
                    for (int v = 0; v < 4; ++v) {
                        const int idx = m * 4 + v;
                        float x0 = acc[m][0][v], x1 = acc[m][1][v];
                        float x2 = acc[m][2][v], x3 = acc[m][3][v];
                        if (diag) {
                            int i = r0 + wr + m * 16 + g * 4 + v;
                            if (jc      == i) x0 = NEG_BIG;
                            if (jc + 16 == i) x1 = NEG_BIG;
                            if (jc + 32 == i) x2 = NEG_BIG;
                            if (jc + 48 == i) x3 = NEG_BIG;
                        }
                        float tm = fmaxf(fmaxf(x0, x1), fmaxf(x2, x3));
                        float cc = tm * C10L2E;
                        float ml = ML2[idx];
                        if (cc > ml + THR_L2) {          // rare rescale (defer-max)
                            S[idx] *= fexp2(ml - cc);
                            ml = cc;
                            ML2[idx] = cc;
                        }
                        S[idx] += fexp2(fmaf(x0, C10L2E, -ml)) + fexp2(fmaf(x1, C10L2E, -ml))
                                + fexp2(fmaf(x2, C10L2E, -ml)) + fexp2(fmaf(x3, C10L2E, -ml));
                    }
                }
            }
        }
    }

    // ---- cross-lane merge within 16-lane groups, store partials ----
    const int slot = blockIdx.y * 4 + (wid & 3);
    #pragma unroll
    for (int idx = 0; idx < 16; ++idx) {
        float m_ = ML2[idx], s_ = S[idx];
        #pragma unroll
        for (int d = 1; d < 16; d <<= 1) {
            float mo = __shfl_xor(m_, d, 64);
            float so = __shfl_xor(s_, d, 64);
            float nm = fmaxf(m_, mo);
            s_ = s_ * fexp2(m_ - nm) + so * fexp2(mo - nm);
            m_ = nm;
        }
        if (l15 == 0) {
            int i = r0 + wr + (idx >> 2) * 16 + g * 4 + (idx & 3);
            float2 val; val.x = m_; val.y = s_;
            *reinterpret_cast<float2*>(part + ((size_t)i * 16 + slot) * 2) = val;
        }
    }
}

// ---------------- combine + final (fused): lse merge, class terms, last-block writes out ----
__global__ void combine_kernel(const float* __restrict__ part, const float* __restrict__ term,
                               float* __restrict__ acc, int* __restrict__ cntr,
                               float* __restrict__ out) {
    __shared__ float sm[16];
    int tid = threadIdx.x;
    int row = blockIdx.x * 16 + (tid >> 4);
    int l16 = tid & 15;
    float2 v = reinterpret_cast<const float2*>(part)[(size_t)row * 16 + l16];
    float m_ = v.x, s_ = v.y;
    #pragma unroll
    for (int d = 1; d < 16; d <<= 1) {
        float mo = __shfl_xor(m_, d, 64);
        float so = __shfl_xor(s_, d, 64);
        float nm = fmaxf(m_, mo);
        s_ = s_ * fexp2(m_ - nm) + so * fexp2(mo - nm);
        m_ = nm;
    }
    if (l16 == 0) sm[tid >> 4] = LN2 * (m_ + flog2(s_));
    __syncthreads();
    if (tid == 0) {
        float a = 0.f;
        #pragma unroll
        for (int i = 0; i < 16; ++i) a += sm[i];
        a -= 10.0f * term[blockIdx.x];
        if (blockIdx.x < 488) a -= 10.0f * term[512 + blockIdx.x];
        atomicAdd(acc, a);
        __threadfence();
        int old = atomicAdd(cntr, 1);
        if (old == 511) {
            __threadfence();
            float tot = atomicAdd(acc, 0.0f);
            out[0] = tot * (0.1f / 8192.0f);
        }
    }
}

extern "C" void kernel_launch(void* const* d_in, const int* in_sizes, int n_in,
                              void* d_out, int out_size, void* d_ws, size_t ws_size,
                              hipStream_t stream) {
    const float* feat = (const float*)d_in[0];    // 8192 x 256 fp32
    const int* labels = (const int*)d_in[1];      // 4096
    float* out = (float*)d_out;

    char* ws = (char*)d_ws;
    ushort_t* Fb = (ushort_t*)ws;                                // 4 MB
    float* part  = (float*)(ws + (4u << 20));                    // 1 MB
    int* cnt     = (int*)(ws + (5u << 20));                      // 4 KB
    float* acc   = (float*)(ws + (5u << 20) + 4096);             // 4 B
    int* cntr    = (int*)(ws + (5u << 20) + 4100);               // 4 B
    int* idxl    = (int*)(ws + (5u << 20) + 8192);               // 256 KB
    float* term  = (float*)(ws + (5u << 20) + 8192 + 262144);    // 4 KB

    hipMemsetAsync(ws + (5u << 20), 0, 8192, stream);            // cnt + acc + cntr
    prep_kernel<<<2048, 256, 0, stream>>>(feat, labels, Fb, cnt, idxl);
    classterm_kernel<<<1000, 64, 0, stream>>>(feat, cnt, idxl, term);
    dim3 grid(64, 4);
    supcon_main<<<grid, 512, 131072, stream>>>(Fb, part);
    combine_kernel<<<512, 256, 0, stream>>>(part, term, acc, cntr, out);
}